// Round 1
// baseline (106.521 us; speedup 1.0000x reference)
//
#include <hip/hip_runtime.h>

#define DEV static __device__ __forceinline__

// ================= lane-exchange primitives =================
// DPP ctrl: 0xB1 quad_perm[1,0,3,2] (xor1) | 0x4E quad_perm[2,3,0,1] (xor2)
//           0x1B quad_perm[3,2,1,0] (xor3) | 0x128 row_ror:8 (xor8)
//           0x140 row_mirror (xor15)       | 0x141 row_half_mirror (xor7)
template <int CTRL>
DEV float dpp_mov(float v) {
    int i = __float_as_int(v);
    i = __builtin_amdgcn_update_dpp(i, i, CTRL, 0xF, 0xF, false);
    return __int_as_float(i);
}
template <int PAT>
DEV float swz(float v) {
    return __int_as_float(__builtin_amdgcn_ds_swizzle(__float_as_int(v), PAT));
}
DEV float bperm(int byteaddr, float v) {
    return __int_as_float(__builtin_amdgcn_ds_bpermute(byteaddr, __float_as_int(v)));
}

#if __has_builtin(__builtin_amdgcn_permlane16_swap)
#define HAVE_PL16 1
// With both operands = v, the two results are {bit16=0-group value bcast,
// bit16=1-group value bcast} in a direction-dependent order (probed at runtime).
DEV void pl16_pair(float v, float &r0, float &r1) {
    auto r = __builtin_amdgcn_permlane16_swap(__float_as_int(v), __float_as_int(v),
                                              false, false);
    r0 = __int_as_float((int)r[0]);
    r1 = __int_as_float((int)r[1]);
}
#endif
#if __has_builtin(__builtin_amdgcn_permlane32_swap)
#define HAVE_PL32 1
DEV void pl32_pair(float v, float &r0, float &r1) {
    auto r = __builtin_amdgcn_permlane32_swap(__float_as_int(v), __float_as_int(v),
                                              false, false);
    r0 = __int_as_float((int)r[0]);
    r1 = __int_as_float((int)r[1]);
}
#endif

// Full-wave sum, all VALU (DPP + permlane swaps); r0+r1 after a swap is
// own+partner regardless of the instruction's swap direction.
DEV float wave_sum(float v, int a32) {
    v += dpp_mov<0xB1>(v);   // + xor1
    v += dpp_mov<0x4E>(v);   // + xor2   (quads now uniform)
    v += dpp_mov<0x141>(v);  // + other quad of the 8-group (xor7 ~ xor4 here)
    v += dpp_mov<0x128>(v);  // + xor8
#ifdef HAVE_PL16
    {
        float r0, r1;
        pl16_pair(v, r0, r1);
        v = r0 + r1;
    }
#else
    v += swz<0x401F>(v);
#endif
#ifdef HAVE_PL32
    {
        float r0, r1;
        pl32_pair(v, r0, r1);
        v = r0 + r1;
    }
#else
    v += bperm(a32, v);
#endif
    return v;
}

// Qubit q <-> bit P = 9-q of state index s = lane*16 + r.
// Lane bits 5..0 = state bits 9..4; reg bits 3..0 = state bits 3..0.
// RY: a0' = c*a0 - s*a1 ; a1' = s*a0 + c*a1.
template <int P>
DEV void apply_ry(float (&re)[16], float (&im)[16], float c, float s, int lane,
                  int a32, bool cv16, bool cv32) {
    if constexpr (P == 9) {
#ifdef HAVE_PL32
        const bool hi = (lane & 32) != 0;
        const float fl = hi ? s : c;   // coeff on bit=0-group value
        const float fh = hi ? c : -s;  // coeff on bit=1-group value
        const float g0 = cv32 ? fl : fh;
        const float g1 = cv32 ? fh : fl;
#pragma unroll
        for (int r = 0; r < 16; ++r) {
            float x0, x1, y0, y1;
            pl32_pair(re[r], x0, x1);
            pl32_pair(im[r], y0, y1);
            re[r] = fmaf(g0, x0, g1 * x1);
            im[r] = fmaf(g0, y0, g1 * y1);
        }
#else
        const float sg = (lane & 32) ? s : -s;
#pragma unroll
        for (int r = 0; r < 16; ++r) {
            float pr = bperm(a32, re[r]);
            float pi = bperm(a32, im[r]);
            re[r] = fmaf(c, re[r], sg * pr);
            im[r] = fmaf(c, im[r], sg * pi);
        }
#endif
    } else if constexpr (P == 8) {
#ifdef HAVE_PL16
        const bool hi = (lane & 16) != 0;
        const float fl = hi ? s : c;
        const float fh = hi ? c : -s;
        const float g0 = cv16 ? fl : fh;
        const float g1 = cv16 ? fh : fl;
#pragma unroll
        for (int r = 0; r < 16; ++r) {
            float x0, x1, y0, y1;
            pl16_pair(re[r], x0, x1);
            pl16_pair(im[r], y0, y1);
            re[r] = fmaf(g0, x0, g1 * x1);
            im[r] = fmaf(g0, y0, g1 * y1);
        }
#else
        const float sg = (lane & 16) ? s : -s;
#pragma unroll
        for (int r = 0; r < 16; ++r) {
            float pr = swz<0x401F>(re[r]);
            float pi = swz<0x401F>(im[r]);
            re[r] = fmaf(c, re[r], sg * pr);
            im[r] = fmaf(c, im[r], sg * pi);
        }
#endif
    } else if constexpr (P >= 4) {
        constexpr int mask = 1 << (P - 4);
        const float sg = (lane & mask) ? s : -s;
#pragma unroll
        for (int r = 0; r < 16; ++r) {
            float pr, pi;
            if constexpr (mask == 8) {
                pr = dpp_mov<0x128>(re[r]);
                pi = dpp_mov<0x128>(im[r]);
            } else if constexpr (mask == 4) {
                // xor4 = xor7 o xor3, both DPP (replaces ds_swizzle)
                pr = dpp_mov<0x1B>(dpp_mov<0x141>(re[r]));
                pi = dpp_mov<0x1B>(dpp_mov<0x141>(im[r]));
            } else if constexpr (mask == 2) {
                pr = dpp_mov<0x4E>(re[r]);
                pi = dpp_mov<0x4E>(im[r]);
            } else {
                pr = dpp_mov<0xB1>(re[r]);
                pi = dpp_mov<0xB1>(im[r]);
            }
            re[r] = fmaf(c, re[r], sg * pr);
            im[r] = fmaf(c, im[r], sg * pi);
        }
    } else {
        constexpr int tb = 1 << P;
#pragma unroll
        for (int r = 0; r < 16; ++r) {
            if (!(r & tb)) {
                const int r2 = r | tb;
                float a0r = re[r], a1r = re[r2];
                float a0i = im[r], a1i = im[r2];
                re[r]  = fmaf(c, a0r, -s * a1r);
                re[r2] = fmaf(s, a0r,  c * a1r);
                im[r]  = fmaf(c, a0i, -s * a1i);
                im[r2] = fmaf(s, a0i,  c * a1i);
            }
        }
    }
}

// Composed lane map of CNOT chain C(q0->q1)..C(q4->q5).
DEV int g_of(int a) {
    a ^= ((a >> 1) & 1) ? 1 : 0;   // C(q4->q5)
    a ^= ((a >> 2) & 1) ? 2 : 0;   // C(q3->q4)
    a ^= ((a >> 3) & 1) ? 4 : 0;   // C(q2->q3)
    a ^= ((a >> 4) & 1) ? 8 : 0;   // C(q1->q2)
    a ^= ((a >> 5) & 1) ? 16 : 0;  // C(q0->q1)
    return a;
}

__global__ __launch_bounds__(256, 4) void dqc_main_kernel(
    const float* __restrict__ x, const float* __restrict__ pre_w,
    const float* __restrict__ pre_b, const float* __restrict__ post_w,
    const float* __restrict__ post_b, const float* __restrict__ w_ry,
    const float* __restrict__ w_rz, float* __restrict__ out, int B) {
    const int lane = threadIdx.x & 63;
    const int wid = threadIdx.x >> 6;
    const int b = blockIdx.x * 4 + wid;
    if (b >= B) return;

    const int a32 = (lane ^ 32) << 2;

    // Probe permlane*_swap direction once (wave-uniform predicate):
    // cv = true  <=> result[0] holds the bit=0-group value broadcast.
    bool cv16 = false, cv32 = false;
#ifdef HAVE_PL16
    {
        auto r = __builtin_amdgcn_permlane16_swap(lane, lane, false, false);
        cv16 = ((int)r[0] == (lane & ~16));
    }
#endif
#ifdef HAVE_PL32
    {
        auto r = __builtin_amdgcn_permlane32_swap(lane, lane, false, false);
        cv32 = ((int)r[0] == (lane & ~32));
    }
#endif

    // Composed CNOT addresses (per-lane, constant over layers).
    const int h0 = lane ^ ((lane & 1) ? 32 : 0);
    const int cA = g_of(h0) << 2;
    const int cB = g_of(h0 ^ 32) << 2;

    // ---- q_in[b, i] = x[b] . pre_w[i] + pre_b[i]  (float4 loads) ----
    float th[10];
#pragma unroll
    for (int i = 0; i < 10; ++i) th[i] = 0.f;
    const float4* xb4 = reinterpret_cast<const float4*>(x + (size_t)b * 512);
    const float4* pw4 = reinterpret_cast<const float4*>(pre_w);
#pragma unroll
    for (int k = 0; k < 2; ++k) {
        const int idx = lane + 64 * k;  // float4 index within 128-wide row
        const float4 xv = xb4[idx];
#pragma unroll
        for (int i = 0; i < 10; ++i) {
            const float4 wv = pw4[i * 128 + idx];
            th[i] = fmaf(xv.x, wv.x, th[i]);
            th[i] = fmaf(xv.y, wv.y, th[i]);
            th[i] = fmaf(xv.z, wv.z, th[i]);
            th[i] = fmaf(xv.w, wv.w, th[i]);
        }
    }
#pragma unroll
    for (int i = 0; i < 10; ++i) th[i] = wave_sum(th[i], a32) + pre_b[i];

    // ---- product state after 10 initial RYs on |0..0>: purely real ----
    float cc[10], ss[10];
#pragma unroll
    for (int i = 0; i < 10; ++i) {
        float a = th[i] * 0.5f;
        cc[i] = __cosf(a);
        ss[i] = __sinf(a);
    }
    float laneP = 1.f;
#pragma unroll
    for (int i = 0; i < 6; ++i)  // qubit i <-> lane bit 5-i
        laneP *= ((lane >> (5 - i)) & 1) ? ss[i] : cc[i];
    float hi4[4], lo4[4];
#pragma unroll
    for (int j = 0; j < 4; ++j) {
        float f6 = (j >> 1) ? ss[6] : cc[6];
        float f7 = (j & 1) ? ss[7] : cc[7];
        hi4[j] = laneP * f6 * f7;
        float f8 = (j >> 1) ? ss[8] : cc[8];
        float f9 = (j & 1) ? ss[9] : cc[9];
        lo4[j] = f8 * f9;
    }
    float re[16], im[16];
#pragma unroll
    for (int r = 0; r < 16; ++r) { re[r] = hi4[r >> 2] * lo4[r & 3]; im[r] = 0.f; }

    // ---- variational layers (trig computed inline; w loads are scalar) ----
#pragma unroll 1
    for (int l = 0; l < 4; ++l) {
        const float* wry = w_ry + l * 10;
        const float* wrz = w_rz + l * 10;

        // All 10 RYs (RZs deferred: RZ(q) commutes with RY(q'!=q))
        {
            float a;
            a = wry[0] * 0.5f; apply_ry<9>(re, im, __cosf(a), __sinf(a), lane, a32, cv16, cv32);
            a = wry[1] * 0.5f; apply_ry<8>(re, im, __cosf(a), __sinf(a), lane, a32, cv16, cv32);
            a = wry[2] * 0.5f; apply_ry<7>(re, im, __cosf(a), __sinf(a), lane, a32, cv16, cv32);
            a = wry[3] * 0.5f; apply_ry<6>(re, im, __cosf(a), __sinf(a), lane, a32, cv16, cv32);
            a = wry[4] * 0.5f; apply_ry<5>(re, im, __cosf(a), __sinf(a), lane, a32, cv16, cv32);
            a = wry[5] * 0.5f; apply_ry<4>(re, im, __cosf(a), __sinf(a), lane, a32, cv16, cv32);
            a = wry[6] * 0.5f; apply_ry<3>(re, im, __cosf(a), __sinf(a), lane, a32, cv16, cv32);
            a = wry[7] * 0.5f; apply_ry<2>(re, im, __cosf(a), __sinf(a), lane, a32, cv16, cv32);
            a = wry[8] * 0.5f; apply_ry<1>(re, im, __cosf(a), __sinf(a), lane, a32, cv16, cv32);
            a = wry[9] * 0.5f; apply_ry<0>(re, im, __cosf(a), __sinf(a), lane, a32, cv16, cv32);
        }

        // Combined diagonal phase for all 10 RZs.
        float zc[10], zs[10];
#pragma unroll
        for (int q = 0; q < 10; ++q) {
            float a = wrz[q] * 0.5f;
            zc[q] = __cosf(a);
            zs[q] = __sinf(a);
        }
        float plr, pli;
        {
            pli = ((lane >> 5) & 1) ? zs[0] : -zs[0];
            plr = zc[0];
#pragma unroll
            for (int q = 1; q < 6; ++q) {
                float sq = ((lane >> (5 - q)) & 1) ? zs[q] : -zs[q];
                float nr = plr * zc[q] - pli * sq;
                float ni = plr * sq + pli * zc[q];
                plr = nr; pli = ni;
            }
        }
        float p67r[4], p67i[4], p89r[4], p89i[4];
        {
            const float c6 = zc[6], s6 = zs[6], c7 = zc[7], s7 = zs[7];
            const float c8 = zc[8], s8 = zs[8], c9 = zc[9], s9 = zs[9];
#pragma unroll
            for (int j = 0; j < 4; ++j) {
                float sg6 = (j >> 1) ? s6 : -s6;  // qubit6 <-> reg bit 3
                float sg7 = (j & 1) ? s7 : -s7;   // qubit7 <-> reg bit 2
                float ar = c6 * c7 - sg6 * sg7;
                float ai = c6 * sg7 + sg6 * c7;
                p67r[j] = ar * plr - ai * pli;    // fold lane phase in
                p67i[j] = ar * pli + ai * plr;
                float sg8 = (j >> 1) ? s8 : -s8;  // qubit8 <-> reg bit 1
                float sg9 = (j & 1) ? s9 : -s9;   // qubit9 <-> reg bit 0
                p89r[j] = c8 * c9 - sg8 * sg9;
                p89i[j] = c8 * sg9 + sg8 * c9;
            }
        }
#pragma unroll
        for (int r = 0; r < 16; ++r) {
            const int j = r >> 2, k = r & 3;
            float t_r = re[r] * p67r[j] - im[r] * p67i[j];
            float t_i = re[r] * p67i[j] + im[r] * p67r[j];
            re[r] = t_r * p89r[k] - t_i * p89i[k];
            im[r] = t_r * p89i[k] + t_i * p89r[k];
        }

        // CNOT ring:
        // (1) composed lane permutation (bpermute is the only general tool)
#pragma unroll
        for (int r = 0; r < 16; ++r) {
            const int addr = ((0x6996 >> r) & 1) ? cB : cA;  // parity of r&15
            re[r] = bperm(addr, re[r]);
            im[r] = bperm(addr, im[r]);
        }
        // (2) C(q5->q6): lane bit0 control, reg bit3 target
        {
            const bool ctrl = (lane & 1) != 0;
#pragma unroll
            for (int r = 0; r < 8; ++r) {
                const int r2 = r | 8;
                float t0 = re[r], t1 = re[r2];
                re[r]  = ctrl ? t1 : t0;
                re[r2] = ctrl ? t0 : t1;
                float u0 = im[r], u1 = im[r2];
                im[r]  = ctrl ? u1 : u0;
                im[r2] = ctrl ? u0 : u1;
            }
        }
        // (3) register renames: C(q6->q7), C(q7->q8), C(q8->q9) — free
#pragma unroll
        for (int r = 0; r < 16; ++r)
            if ((r & 8) && !(r & 4)) {
                const int r2 = r | 4;
                float t = re[r]; re[r] = re[r2]; re[r2] = t;
                t = im[r]; im[r] = im[r2]; im[r2] = t;
            }
#pragma unroll
        for (int r = 0; r < 16; ++r)
            if ((r & 4) && !(r & 2)) {
                const int r2 = r | 2;
                float t = re[r]; re[r] = re[r2]; re[r2] = t;
                t = im[r]; im[r] = im[r2]; im[r2] = t;
            }
#pragma unroll
        for (int r = 0; r < 16; ++r)
            if ((r & 2) && !(r & 1)) {
                const int r2 = r | 1;
                float t = re[r]; re[r] = re[r2]; re[r2] = t;
                t = im[r]; im[r] = im[r2]; im[r2] = t;
            }
    }

    // ---- out[b] = sum_s |psi_s|^2 * sum_j post_w[j]*(1-2*bit_j(s)) + post_b ----
    float laneC = 0.f;
#pragma unroll
    for (int j = 0; j < 6; ++j) {
        int bit = (lane >> (5 - j)) & 1;
        laneC += post_w[j] * (1.f - 2.f * (float)bit);
    }
    float acc = 0.f;
#pragma unroll
    for (int r = 0; r < 16; ++r) {
        float regC = 0.f;
#pragma unroll
        for (int j = 6; j < 10; ++j) {
            int bit = (r >> (9 - j)) & 1;
            regC += post_w[j] * (1.f - 2.f * (float)bit);
        }
        float p = fmaf(re[r], re[r], im[r] * im[r]);
        acc = fmaf(p, laneC + regC, acc);
    }
    acc = wave_sum(acc, a32);
    if (lane == 0) out[b] = acc + post_b[0];
}

extern "C" void kernel_launch(void* const* d_in, const int* in_sizes, int n_in,
                              void* d_out, int out_size, void* d_ws, size_t ws_size,
                              hipStream_t stream) {
    const float* x      = (const float*)d_in[0];
    const float* pre_w  = (const float*)d_in[1];
    const float* pre_b  = (const float*)d_in[2];
    const float* post_w = (const float*)d_in[3];
    const float* post_b = (const float*)d_in[4];
    const float* w_ry   = (const float*)d_in[5];
    const float* w_rz   = (const float*)d_in[6];
    float* out = (float*)d_out;
    (void)d_ws; (void)ws_size;

    const int B = in_sizes[0] / 512;  // 4096

    dqc_main_kernel<<<(B + 3) / 4, 256, 0, stream>>>(x, pre_w, pre_b, post_w,
                                                     post_b, w_ry, w_rz, out, B);
}

// Round 2
// 99.225 us; speedup vs baseline: 1.0735x; 1.0735x over previous
//
#include <hip/hip_runtime.h>

#define DEV static __device__ __forceinline__

// ================= lane-exchange primitives =================
// DPP ctrl: 0xB1 quad_perm[1,0,3,2] (xor1) | 0x4E quad_perm[2,3,0,1] (xor2)
//           0x1B quad_perm[3,2,1,0] (xor3) | 0x128 row_ror:8 (xor8)
//           0x140 row_mirror (xor15)       | 0x141 row_half_mirror (xor7)
template <int CTRL>
DEV float dpp_mov(float v) {
    int i = __float_as_int(v);
    i = __builtin_amdgcn_update_dpp(i, i, CTRL, 0xF, 0xF, false);
    return __int_as_float(i);
}
template <int PAT>
DEV float swz(float v) {
    return __int_as_float(__builtin_amdgcn_ds_swizzle(__float_as_int(v), PAT));
}
DEV float bperm(int byteaddr, float v) {
    return __int_as_float(__builtin_amdgcn_ds_bpermute(byteaddr, __float_as_int(v)));
}

#if __has_builtin(__builtin_amdgcn_permlane16_swap)
#define HAVE_PL16 1
DEV void pl16_pair(float v, float &r0, float &r1) {
    auto r = __builtin_amdgcn_permlane16_swap(__float_as_int(v), __float_as_int(v),
                                              false, false);
    r0 = __int_as_float((int)r[0]);
    r1 = __int_as_float((int)r[1]);
}
#endif
#if __has_builtin(__builtin_amdgcn_permlane32_swap)
#define HAVE_PL32 1
DEV void pl32_pair(float v, float &r0, float &r1) {
    auto r = __builtin_amdgcn_permlane32_swap(__float_as_int(v), __float_as_int(v),
                                              false, false);
    r0 = __int_as_float((int)r[0]);
    r1 = __int_as_float((int)r[1]);
}
#endif

// Full-wave sum; r0+r1 after a swap is own+partner regardless of direction.
DEV float wave_sum(float v, int a32) {
    v += dpp_mov<0xB1>(v);
    v += dpp_mov<0x4E>(v);
    v += dpp_mov<0x141>(v);
    v += dpp_mov<0x128>(v);
#ifdef HAVE_PL16
    {
        float r0, r1;
        pl16_pair(v, r0, r1);
        v = r0 + r1;
    }
#else
    v += swz<0x401F>(v);
#endif
#ifdef HAVE_PL32
    {
        float r0, r1;
        pl32_pair(v, r0, r1);
        v = r0 + r1;
    }
#else
    v += bperm(a32, v);
#endif
    return v;
}

// Qubit q <-> bit P = 9-q of state index s = lane*16 + r.
// Lane bits 5..0 = state bits 9..4; reg bits 3..0 = state bits 3..0.

template <int P>
DEV void apply_ry(float (&re)[16], float (&im)[16], float c, float s, int lane,
                  int a32, bool cv16, bool cv32) {
    if constexpr (P == 9) {
#ifdef HAVE_PL32
        const bool hi = (lane & 32) != 0;
        const float fl = hi ? s : c;
        const float fh = hi ? c : -s;
        const float g0 = cv32 ? fl : fh;
        const float g1 = cv32 ? fh : fl;
#pragma unroll
        for (int r = 0; r < 16; ++r) {
            float x0, x1, y0, y1;
            pl32_pair(re[r], x0, x1);
            pl32_pair(im[r], y0, y1);
            re[r] = fmaf(g0, x0, g1 * x1);
            im[r] = fmaf(g0, y0, g1 * y1);
        }
#else
        const float sg = (lane & 32) ? s : -s;
#pragma unroll
        for (int r = 0; r < 16; ++r) {
            float pr = bperm(a32, re[r]);
            float pi = bperm(a32, im[r]);
            re[r] = fmaf(c, re[r], sg * pr);
            im[r] = fmaf(c, im[r], sg * pi);
        }
#endif
    } else if constexpr (P == 8) {
#ifdef HAVE_PL16
        const bool hi = (lane & 16) != 0;
        const float fl = hi ? s : c;
        const float fh = hi ? c : -s;
        const float g0 = cv16 ? fl : fh;
        const float g1 = cv16 ? fh : fl;
#pragma unroll
        for (int r = 0; r < 16; ++r) {
            float x0, x1, y0, y1;
            pl16_pair(re[r], x0, x1);
            pl16_pair(im[r], y0, y1);
            re[r] = fmaf(g0, x0, g1 * x1);
            im[r] = fmaf(g0, y0, g1 * y1);
        }
#else
        const float sg = (lane & 16) ? s : -s;
#pragma unroll
        for (int r = 0; r < 16; ++r) {
            float pr = swz<0x401F>(re[r]);
            float pi = swz<0x401F>(im[r]);
            re[r] = fmaf(c, re[r], sg * pr);
            im[r] = fmaf(c, im[r], sg * pi);
        }
#endif
    } else if constexpr (P >= 4) {
        constexpr int mask = 1 << (P - 4);
        const float sg = (lane & mask) ? s : -s;
#pragma unroll
        for (int r = 0; r < 16; ++r) {
            float pr, pi;
            if constexpr (mask == 8) {
                pr = dpp_mov<0x128>(re[r]);
                pi = dpp_mov<0x128>(im[r]);
            } else if constexpr (mask == 4) {
                pr = dpp_mov<0x1B>(dpp_mov<0x141>(re[r]));
                pi = dpp_mov<0x1B>(dpp_mov<0x141>(im[r]));
            } else if constexpr (mask == 2) {
                pr = dpp_mov<0x4E>(re[r]);
                pi = dpp_mov<0x4E>(im[r]);
            } else {
                pr = dpp_mov<0xB1>(re[r]);
                pi = dpp_mov<0xB1>(im[r]);
            }
            re[r] = fmaf(c, re[r], sg * pr);
            im[r] = fmaf(c, im[r], sg * pi);
        }
    } else {
        constexpr int tb = 1 << P;
#pragma unroll
        for (int r = 0; r < 16; ++r) {
            if (!(r & tb)) {
                const int r2 = r | tb;
                float a0r = re[r], a1r = re[r2];
                float a0i = im[r], a1i = im[r2];
                re[r]  = fmaf(c, a0r, -s * a1r);
                re[r2] = fmaf(s, a0r,  c * a1r);
                im[r]  = fmaf(c, a0i, -s * a1i);
                im[r2] = fmaf(s, a0i,  c * a1i);
            }
        }
    }
}

// Real-state variant (layer 0: state stays purely real through all its RYs).
template <int P>
DEV void apply_ry_real(float (&re)[16], float c, float s, int lane, int a32,
                       bool cv16, bool cv32) {
    if constexpr (P == 9) {
#ifdef HAVE_PL32
        const bool hi = (lane & 32) != 0;
        const float fl = hi ? s : c;
        const float fh = hi ? c : -s;
        const float g0 = cv32 ? fl : fh;
        const float g1 = cv32 ? fh : fl;
#pragma unroll
        for (int r = 0; r < 16; ++r) {
            float x0, x1;
            pl32_pair(re[r], x0, x1);
            re[r] = fmaf(g0, x0, g1 * x1);
        }
#else
        const float sg = (lane & 32) ? s : -s;
#pragma unroll
        for (int r = 0; r < 16; ++r) {
            float pr = bperm(a32, re[r]);
            re[r] = fmaf(c, re[r], sg * pr);
        }
#endif
    } else if constexpr (P == 8) {
#ifdef HAVE_PL16
        const bool hi = (lane & 16) != 0;
        const float fl = hi ? s : c;
        const float fh = hi ? c : -s;
        const float g0 = cv16 ? fl : fh;
        const float g1 = cv16 ? fh : fl;
#pragma unroll
        for (int r = 0; r < 16; ++r) {
            float x0, x1;
            pl16_pair(re[r], x0, x1);
            re[r] = fmaf(g0, x0, g1 * x1);
        }
#else
        const float sg = (lane & 16) ? s : -s;
#pragma unroll
        for (int r = 0; r < 16; ++r) {
            float pr = swz<0x401F>(re[r]);
            re[r] = fmaf(c, re[r], sg * pr);
        }
#endif
    } else if constexpr (P >= 4) {
        constexpr int mask = 1 << (P - 4);
        const float sg = (lane & mask) ? s : -s;
#pragma unroll
        for (int r = 0; r < 16; ++r) {
            float pr;
            if constexpr (mask == 8) {
                pr = dpp_mov<0x128>(re[r]);
            } else if constexpr (mask == 4) {
                pr = dpp_mov<0x1B>(dpp_mov<0x141>(re[r]));
            } else if constexpr (mask == 2) {
                pr = dpp_mov<0x4E>(re[r]);
            } else {
                pr = dpp_mov<0xB1>(re[r]);
            }
            re[r] = fmaf(c, re[r], sg * pr);
        }
    } else {
        constexpr int tb = 1 << P;
#pragma unroll
        for (int r = 0; r < 16; ++r) {
            if (!(r & tb)) {
                const int r2 = r | tb;
                float a0 = re[r], a1 = re[r2];
                re[r]  = fmaf(c, a0, -s * a1);
                re[r2] = fmaf(s, a0,  c * a1);
            }
        }
    }
}

// Composed lane map of CNOT chain C(q0->q1)..C(q4->q5).
DEV int g_of(int a) {
    a ^= ((a >> 1) & 1) ? 1 : 0;
    a ^= ((a >> 2) & 1) ? 2 : 0;
    a ^= ((a >> 3) & 1) ? 4 : 0;
    a ^= ((a >> 4) & 1) ? 8 : 0;
    a ^= ((a >> 5) & 1) ? 16 : 0;
    return a;
}

// Build the two per-r phase factor tables from the RZ trig of one layer.
// p67 has the q0..q5 lane phase folded in.
DEV void build_rz_tables(const float (&zc)[10], const float (&zs)[10], int lane,
                         float (&p67r)[4], float (&p67i)[4], float (&p89r)[4],
                         float (&p89i)[4]) {
    float plr, pli;
    pli = ((lane >> 5) & 1) ? zs[0] : -zs[0];
    plr = zc[0];
#pragma unroll
    for (int q = 1; q < 6; ++q) {
        float sq = ((lane >> (5 - q)) & 1) ? zs[q] : -zs[q];
        float nr = plr * zc[q] - pli * sq;
        float ni = plr * sq + pli * zc[q];
        plr = nr; pli = ni;
    }
    const float c6 = zc[6], s6 = zs[6], c7 = zc[7], s7 = zs[7];
    const float c8 = zc[8], s8 = zs[8], c9 = zc[9], s9 = zs[9];
#pragma unroll
    for (int j = 0; j < 4; ++j) {
        float sg6 = (j >> 1) ? s6 : -s6;  // qubit6 <-> reg bit 3
        float sg7 = (j & 1) ? s7 : -s7;   // qubit7 <-> reg bit 2
        float ar = c6 * c7 - sg6 * sg7;
        float ai = c6 * sg7 + sg6 * c7;
        p67r[j] = ar * plr - ai * pli;
        p67i[j] = ar * pli + ai * plr;
        float sg8 = (j >> 1) ? s8 : -s8;  // qubit8 <-> reg bit 1
        float sg9 = (j & 1) ? s9 : -s9;   // qubit9 <-> reg bit 0
        p89r[j] = c8 * c9 - sg8 * sg9;
        p89i[j] = c8 * sg9 + sg8 * c9;
    }
}

// CNOT ring (physical): composed lane perm + conditional reg swap + renames.
DEV void cnot_ring(float (&re)[16], float (&im)[16], int cA, int cB, int lane) {
#pragma unroll
    for (int r = 0; r < 16; ++r) {
        const int addr = ((0x6996 >> r) & 1) ? cB : cA;  // parity of r&15
        re[r] = bperm(addr, re[r]);
        im[r] = bperm(addr, im[r]);
    }
    {
        const bool ctrl = (lane & 1) != 0;  // C(q5->q6)
#pragma unroll
        for (int r = 0; r < 8; ++r) {
            const int r2 = r | 8;
            float t0 = re[r], t1 = re[r2];
            re[r]  = ctrl ? t1 : t0;
            re[r2] = ctrl ? t0 : t1;
            float u0 = im[r], u1 = im[r2];
            im[r]  = ctrl ? u1 : u0;
            im[r2] = ctrl ? u0 : u1;
        }
    }
#pragma unroll
    for (int r = 0; r < 16; ++r)
        if ((r & 8) && !(r & 4)) {
            const int r2 = r | 4;
            float t = re[r]; re[r] = re[r2]; re[r2] = t;
            t = im[r]; im[r] = im[r2]; im[r2] = t;
        }
#pragma unroll
    for (int r = 0; r < 16; ++r)
        if ((r & 4) && !(r & 2)) {
            const int r2 = r | 2;
            float t = re[r]; re[r] = re[r2]; re[r2] = t;
            t = im[r]; im[r] = im[r2]; im[r2] = t;
        }
#pragma unroll
    for (int r = 0; r < 16; ++r)
        if ((r & 2) && !(r & 1)) {
            const int r2 = r | 1;
            float t = re[r]; re[r] = re[r2]; re[r2] = t;
            t = im[r]; im[r] = im[r2]; im[r2] = t;
        }
}

__global__ __launch_bounds__(256, 4) void dqc_main_kernel(
    const float* __restrict__ x, const float* __restrict__ pre_w,
    const float* __restrict__ pre_b, const float* __restrict__ post_w,
    const float* __restrict__ post_b, const float* __restrict__ w_ry,
    const float* __restrict__ w_rz, float* __restrict__ out, int B) {
    // Block-shared weight trig (batch-independent): [0..39] RY, [40..79] RZ,
    // index l*10+q within each half.
    __shared__ float2 sh_trig[80];
    {
        int t = threadIdx.x;
        if (t < 80) {
            float ang = (t < 40 ? w_ry[t] : w_rz[t - 40]) * 0.5f;
            float sv, cv;
            __sincosf(ang, &sv, &cv);
            sh_trig[t] = make_float2(cv, sv);
        }
    }
    __syncthreads();

    const int lane = threadIdx.x & 63;
    const int wid = threadIdx.x >> 6;
    const int b = blockIdx.x * 4 + wid;
    if (b >= B) return;

    const int a32 = (lane ^ 32) << 2;

    // Probe permlane*_swap direction (wave-uniform).
    bool cv16 = false, cv32 = false;
#ifdef HAVE_PL16
    {
        auto r = __builtin_amdgcn_permlane16_swap(lane, lane, false, false);
        cv16 = ((int)r[0] == (lane & ~16));
    }
#endif
#ifdef HAVE_PL32
    {
        auto r = __builtin_amdgcn_permlane32_swap(lane, lane, false, false);
        cv32 = ((int)r[0] == (lane & ~32));
    }
#endif

    const int h0 = lane ^ ((lane & 1) ? 32 : 0);
    const int cA = g_of(h0) << 2;
    const int cB = g_of(h0 ^ 32) << 2;

    // ---- q_in[b, i] = x[b] . pre_w[i] + pre_b[i]  (float4 loads) ----
    float th[10];
#pragma unroll
    for (int i = 0; i < 10; ++i) th[i] = 0.f;
    const float4* xb4 = reinterpret_cast<const float4*>(x + (size_t)b * 512);
    const float4* pw4 = reinterpret_cast<const float4*>(pre_w);
#pragma unroll
    for (int k = 0; k < 2; ++k) {
        const int idx = lane + 64 * k;
        const float4 xv = xb4[idx];
#pragma unroll
        for (int i = 0; i < 10; ++i) {
            const float4 wv = pw4[i * 128 + idx];
            th[i] = fmaf(xv.x, wv.x, th[i]);
            th[i] = fmaf(xv.y, wv.y, th[i]);
            th[i] = fmaf(xv.z, wv.z, th[i]);
            th[i] = fmaf(xv.w, wv.w, th[i]);
        }
    }
#pragma unroll
    for (int i = 0; i < 10; ++i) th[i] = wave_sum(th[i], a32) + pre_b[i];

    // ---- product state after 10 initial RYs on |0..0>: purely real ----
    float cc[10], ss[10];
#pragma unroll
    for (int i = 0; i < 10; ++i) {
        float sv, cv;
        __sincosf(th[i] * 0.5f, &sv, &cv);
        cc[i] = cv;
        ss[i] = sv;
    }
    float laneP = 1.f;
#pragma unroll
    for (int i = 0; i < 6; ++i)
        laneP *= ((lane >> (5 - i)) & 1) ? ss[i] : cc[i];
    float hi4[4], lo4[4];
#pragma unroll
    for (int j = 0; j < 4; ++j) {
        float f6 = (j >> 1) ? ss[6] : cc[6];
        float f7 = (j & 1) ? ss[7] : cc[7];
        hi4[j] = laneP * f6 * f7;
        float f8 = (j >> 1) ? ss[8] : cc[8];
        float f9 = (j & 1) ? ss[9] : cc[9];
        lo4[j] = f8 * f9;
    }
    float re[16], im[16];
#pragma unroll
    for (int r = 0; r < 16; ++r) re[r] = hi4[r >> 2] * lo4[r & 3];

    // ================= layer 0: state is REAL through all RYs =============
    {
        float yc[10], ys[10];
#pragma unroll
        for (int q = 0; q < 10; ++q) {
            float2 v = sh_trig[q];
            yc[q] = v.x; ys[q] = v.y;
        }
        apply_ry_real<9>(re, yc[0], ys[0], lane, a32, cv16, cv32);
        apply_ry_real<8>(re, yc[1], ys[1], lane, a32, cv16, cv32);
        apply_ry_real<7>(re, yc[2], ys[2], lane, a32, cv16, cv32);
        apply_ry_real<6>(re, yc[3], ys[3], lane, a32, cv16, cv32);
        apply_ry_real<5>(re, yc[4], ys[4], lane, a32, cv16, cv32);
        apply_ry_real<4>(re, yc[5], ys[5], lane, a32, cv16, cv32);
        apply_ry_real<3>(re, yc[6], ys[6], lane, a32, cv16, cv32);
        apply_ry_real<2>(re, yc[7], ys[7], lane, a32, cv16, cv32);
        apply_ry_real<1>(re, yc[8], ys[8], lane, a32, cv16, cv32);
        apply_ry_real<0>(re, yc[9], ys[9], lane, a32, cv16, cv32);

        // First RZ: real -> complex (re' = re*P_r, im' = re*P_i)
        float zc[10], zs[10];
#pragma unroll
        for (int q = 0; q < 10; ++q) {
            float2 v = sh_trig[40 + q];
            zc[q] = v.x; zs[q] = v.y;
        }
        float p67r[4], p67i[4], p89r[4], p89i[4];
        build_rz_tables(zc, zs, lane, p67r, p67i, p89r, p89i);
#pragma unroll
        for (int r = 0; r < 16; ++r) {
            const int j = r >> 2, k = r & 3;
            float Ar = p67r[j] * p89r[k] - p67i[j] * p89i[k];
            float Ai = p67r[j] * p89i[k] + p67i[j] * p89r[k];
            float t = re[r];
            re[r] = t * Ar;
            im[r] = t * Ai;
        }
        cnot_ring(re, im, cA, cB, lane);
    }

    // ================= layers 1..3 (complex) =============================
#pragma unroll 1
    for (int l = 1; l < 4; ++l) {
        float yc[10], ys[10], zc[10], zs[10];
#pragma unroll
        for (int q = 0; q < 10; ++q) {
            float2 v = sh_trig[l * 10 + q];
            yc[q] = v.x; ys[q] = v.y;
            float2 w = sh_trig[40 + l * 10 + q];
            zc[q] = w.x; zs[q] = w.y;
        }
        apply_ry<9>(re, im, yc[0], ys[0], lane, a32, cv16, cv32);
        apply_ry<8>(re, im, yc[1], ys[1], lane, a32, cv16, cv32);
        apply_ry<7>(re, im, yc[2], ys[2], lane, a32, cv16, cv32);
        apply_ry<6>(re, im, yc[3], ys[3], lane, a32, cv16, cv32);
        apply_ry<5>(re, im, yc[4], ys[4], lane, a32, cv16, cv32);
        apply_ry<4>(re, im, yc[5], ys[5], lane, a32, cv16, cv32);
        apply_ry<3>(re, im, yc[6], ys[6], lane, a32, cv16, cv32);
        apply_ry<2>(re, im, yc[7], ys[7], lane, a32, cv16, cv32);
        apply_ry<1>(re, im, yc[8], ys[8], lane, a32, cv16, cv32);
        apply_ry<0>(re, im, yc[9], ys[9], lane, a32, cv16, cv32);

        float p67r[4], p67i[4], p89r[4], p89i[4];
        build_rz_tables(zc, zs, lane, p67r, p67i, p89r, p89i);
#pragma unroll
        for (int r = 0; r < 16; ++r) {
            const int j = r >> 2, k = r & 3;
            float t_r = re[r] * p67r[j] - im[r] * p67i[j];
            float t_i = re[r] * p67i[j] + im[r] * p67r[j];
            re[r] = t_r * p89r[k] - t_i * p89i[k];
            im[r] = t_r * p89i[k] + t_i * p89r[k];
        }
        cnot_ring(re, im, cA, cB, lane);
    }

    // ---- out[b] = sum_s |psi_s|^2 * C(s) + post_b ----
    float laneC = 0.f;
#pragma unroll
    for (int j = 0; j < 6; ++j) {
        int bit = (lane >> (5 - j)) & 1;
        laneC += post_w[j] * (1.f - 2.f * (float)bit);
    }
    const float w6 = post_w[6], w7 = post_w[7], w8 = post_w[8], w9 = post_w[9];
    float base67[4], m89[4];
#pragma unroll
    for (int j = 0; j < 4; ++j) {
        base67[j] = laneC + ((j >> 1) ? -w6 : w6) + ((j & 1) ? -w7 : w7);
        m89[j] = ((j >> 1) ? -w8 : w8) + ((j & 1) ? -w9 : w9);
    }
    float acc = 0.f;
#pragma unroll
    for (int r = 0; r < 16; ++r) {
        float p = fmaf(re[r], re[r], im[r] * im[r]);
        acc = fmaf(p, base67[r >> 2] + m89[r & 3], acc);
    }
    acc = wave_sum(acc, a32);
    if (lane == 0) out[b] = acc + post_b[0];
}

extern "C" void kernel_launch(void* const* d_in, const int* in_sizes, int n_in,
                              void* d_out, int out_size, void* d_ws, size_t ws_size,
                              hipStream_t stream) {
    const float* x      = (const float*)d_in[0];
    const float* pre_w  = (const float*)d_in[1];
    const float* pre_b  = (const float*)d_in[2];
    const float* post_w = (const float*)d_in[3];
    const float* post_b = (const float*)d_in[4];
    const float* w_ry   = (const float*)d_in[5];
    const float* w_rz   = (const float*)d_in[6];
    float* out = (float*)d_out;
    (void)d_ws; (void)ws_size;

    const int B = in_sizes[0] / 512;  // 4096

    dqc_main_kernel<<<(B + 3) / 4, 256, 0, stream>>>(x, pre_w, pre_b, post_w,
                                                     post_b, w_ry, w_rz, out, B);
}

// Round 3
// 95.824 us; speedup vs baseline: 1.1116x; 1.0355x over previous
//
#include <hip/hip_runtime.h>

#define DEV static __device__ __forceinline__

// ================= lane-exchange primitives =================
// DPP ctrl: 0xB1 quad_perm[1,0,3,2] (xor1) | 0x4E quad_perm[2,3,0,1] (xor2)
//           0x1B quad_perm[3,2,1,0] (xor3) | 0x128 row_ror:8 (xor8)
//           0x141 row_half_mirror (xor7)
template <int CTRL>
DEV float dpp_mov(float v) {
    int i = __float_as_int(v);
    i = __builtin_amdgcn_update_dpp(i, i, CTRL, 0xF, 0xF, false);
    return __int_as_float(i);
}
template <int PAT>
DEV float swz(float v) {
    return __int_as_float(__builtin_amdgcn_ds_swizzle(__float_as_int(v), PAT));
}
DEV float bperm(int byteaddr, float v) {
    return __int_as_float(__builtin_amdgcn_ds_bpermute(byteaddr, __float_as_int(v)));
}

#if __has_builtin(__builtin_amdgcn_permlane16_swap)
#define HAVE_PL16 1
DEV void pl16_pair(float v, float &r0, float &r1) {
    auto r = __builtin_amdgcn_permlane16_swap(__float_as_int(v), __float_as_int(v),
                                              false, false);
    r0 = __int_as_float((int)r[0]);
    r1 = __int_as_float((int)r[1]);
}
#endif
#if __has_builtin(__builtin_amdgcn_permlane32_swap)
#define HAVE_PL32 1
DEV void pl32_pair(float v, float &r0, float &r1) {
    auto r = __builtin_amdgcn_permlane32_swap(__float_as_int(v), __float_as_int(v),
                                              false, false);
    r0 = __int_as_float((int)r[0]);
    r1 = __int_as_float((int)r[1]);
}
#endif

// Full-wave sum; r0+r1 after a swap is own+partner regardless of direction.
DEV float wave_sum(float v, int a32) {
    v += dpp_mov<0xB1>(v);
    v += dpp_mov<0x4E>(v);
    v += dpp_mov<0x141>(v);
    v += dpp_mov<0x128>(v);
#ifdef HAVE_PL16
    {
        float r0, r1;
        pl16_pair(v, r0, r1);
        v = r0 + r1;
    }
#else
    v += swz<0x401F>(v);
#endif
#ifdef HAVE_PL32
    {
        float r0, r1;
        pl32_pair(v, r0, r1);
        v = r0 + r1;
    }
#else
    v += bperm(a32, v);
#endif
    return v;
}

// Qubit q <-> bit P = 9-q of state index s = lane*16 + r.
// Lane bits 5..0 = state bits 9..4; reg bits 3..0 = state bits 3..0.
template <int P>
DEV void apply_ry(float (&re)[16], float (&im)[16], float c, float s, int lane,
                  int a32, bool cv16, bool cv32) {
    if constexpr (P == 9) {
#ifdef HAVE_PL32
        const bool hi = (lane & 32) != 0;
        const float fl = hi ? s : c;
        const float fh = hi ? c : -s;
        const float g0 = cv32 ? fl : fh;
        const float g1 = cv32 ? fh : fl;
#pragma unroll
        for (int r = 0; r < 16; ++r) {
            float x0, x1, y0, y1;
            pl32_pair(re[r], x0, x1);
            pl32_pair(im[r], y0, y1);
            re[r] = fmaf(g0, x0, g1 * x1);
            im[r] = fmaf(g0, y0, g1 * y1);
        }
#else
        const float sg = (lane & 32) ? s : -s;
#pragma unroll
        for (int r = 0; r < 16; ++r) {
            float pr = bperm(a32, re[r]);
            float pi = bperm(a32, im[r]);
            re[r] = fmaf(c, re[r], sg * pr);
            im[r] = fmaf(c, im[r], sg * pi);
        }
#endif
    } else if constexpr (P == 8) {
#ifdef HAVE_PL16
        const bool hi = (lane & 16) != 0;
        const float fl = hi ? s : c;
        const float fh = hi ? c : -s;
        const float g0 = cv16 ? fl : fh;
        const float g1 = cv16 ? fh : fl;
#pragma unroll
        for (int r = 0; r < 16; ++r) {
            float x0, x1, y0, y1;
            pl16_pair(re[r], x0, x1);
            pl16_pair(im[r], y0, y1);
            re[r] = fmaf(g0, x0, g1 * x1);
            im[r] = fmaf(g0, y0, g1 * y1);
        }
#else
        const float sg = (lane & 16) ? s : -s;
#pragma unroll
        for (int r = 0; r < 16; ++r) {
            float pr = swz<0x401F>(re[r]);
            float pi = swz<0x401F>(im[r]);
            re[r] = fmaf(c, re[r], sg * pr);
            im[r] = fmaf(c, im[r], sg * pi);
        }
#endif
    } else if constexpr (P >= 4) {
        constexpr int mask = 1 << (P - 4);
        const float sg = (lane & mask) ? s : -s;
#pragma unroll
        for (int r = 0; r < 16; ++r) {
            float pr, pi;
            if constexpr (mask == 8) {
                pr = dpp_mov<0x128>(re[r]);
                pi = dpp_mov<0x128>(im[r]);
            } else if constexpr (mask == 4) {
                // ds_swizzle BitMode xor=4 (LDS pipe - nearly idle)
                pr = swz<0x101F>(re[r]);
                pi = swz<0x101F>(im[r]);
            } else if constexpr (mask == 2) {
                pr = dpp_mov<0x4E>(re[r]);
                pi = dpp_mov<0x4E>(im[r]);
            } else {
                pr = dpp_mov<0xB1>(re[r]);
                pi = dpp_mov<0xB1>(im[r]);
            }
            re[r] = fmaf(c, re[r], sg * pr);
            im[r] = fmaf(c, im[r], sg * pi);
        }
    } else {
        constexpr int tb = 1 << P;
#pragma unroll
        for (int r = 0; r < 16; ++r) {
            if (!(r & tb)) {
                const int r2 = r | tb;
                float a0r = re[r], a1r = re[r2];
                float a0i = im[r], a1i = im[r2];
                re[r]  = fmaf(c, a0r, -s * a1r);
                re[r2] = fmaf(s, a0r,  c * a1r);
                im[r]  = fmaf(c, a0i, -s * a1i);
                im[r2] = fmaf(s, a0i,  c * a1i);
            }
        }
    }
}

// Composed lane map of CNOT chain C(q0->q1)..C(q4->q5).
DEV int g_of(int a) {
    a ^= ((a >> 1) & 1) ? 1 : 0;
    a ^= ((a >> 2) & 1) ? 2 : 0;
    a ^= ((a >> 3) & 1) ? 4 : 0;
    a ^= ((a >> 4) & 1) ? 8 : 0;
    a ^= ((a >> 5) & 1) ? 16 : 0;
    return a;
}

// RZ phase tables for one layer (p67 has the q0..q5 lane phase folded in).
DEV void build_rz_tables(const float (&zc)[10], const float (&zs)[10], int lane,
                         float (&p67r)[4], float (&p67i)[4], float (&p89r)[4],
                         float (&p89i)[4]) {
    float plr, pli;
    pli = ((lane >> 5) & 1) ? zs[0] : -zs[0];
    plr = zc[0];
#pragma unroll
    for (int q = 1; q < 6; ++q) {
        float sq = ((lane >> (5 - q)) & 1) ? zs[q] : -zs[q];
        float nr = plr * zc[q] - pli * sq;
        float ni = plr * sq + pli * zc[q];
        plr = nr; pli = ni;
    }
    const float c6 = zc[6], s6 = zs[6], c7 = zc[7], s7 = zs[7];
    const float c8 = zc[8], s8 = zs[8], c9 = zc[9], s9 = zs[9];
#pragma unroll
    for (int j = 0; j < 4; ++j) {
        float sg6 = (j >> 1) ? s6 : -s6;  // qubit6 <-> reg bit 3
        float sg7 = (j & 1) ? s7 : -s7;   // qubit7 <-> reg bit 2
        float ar = c6 * c7 - sg6 * sg7;
        float ai = c6 * sg7 + sg6 * c7;
        p67r[j] = ar * plr - ai * pli;
        p67i[j] = ar * pli + ai * plr;
        float sg8 = (j >> 1) ? s8 : -s8;  // qubit8 <-> reg bit 1
        float sg9 = (j & 1) ? s9 : -s9;   // qubit9 <-> reg bit 0
        p89r[j] = c8 * c9 - sg8 * sg9;
        p89i[j] = c8 * sg9 + sg8 * c9;
    }
}

// CNOT ring (physical): composed lane perm + conditional reg swap + renames.
// Renames are free when the surrounding code is fully unrolled.
DEV void cnot_ring(float (&re)[16], float (&im)[16], int cA, int cB, int lane) {
#pragma unroll
    for (int r = 0; r < 16; ++r) {
        const int addr = ((0x6996 >> r) & 1) ? cB : cA;  // parity of r&15
        re[r] = bperm(addr, re[r]);
        im[r] = bperm(addr, im[r]);
    }
    {
        const bool ctrl = (lane & 1) != 0;  // C(q5->q6)
#pragma unroll
        for (int r = 0; r < 8; ++r) {
            const int r2 = r | 8;
            float t0 = re[r], t1 = re[r2];
            re[r]  = ctrl ? t1 : t0;
            re[r2] = ctrl ? t0 : t1;
            float u0 = im[r], u1 = im[r2];
            im[r]  = ctrl ? u1 : u0;
            im[r2] = ctrl ? u0 : u1;
        }
    }
#pragma unroll
    for (int r = 0; r < 16; ++r)
        if ((r & 8) && !(r & 4)) {
            const int r2 = r | 4;
            float t = re[r]; re[r] = re[r2]; re[r2] = t;
            t = im[r]; im[r] = im[r2]; im[r2] = t;
        }
#pragma unroll
    for (int r = 0; r < 16; ++r)
        if ((r & 4) && !(r & 2)) {
            const int r2 = r | 2;
            float t = re[r]; re[r] = re[r2]; re[r2] = t;
            t = im[r]; im[r] = im[r2]; im[r2] = t;
        }
#pragma unroll
    for (int r = 0; r < 16; ++r)
        if ((r & 2) && !(r & 1)) {
            const int r2 = r | 1;
            float t = re[r]; re[r] = re[r2]; re[r2] = t;
            t = im[r]; im[r] = im[r2]; im[r2] = t;
        }
}

__global__ __launch_bounds__(256, 4) void dqc_main_kernel(
    const float* __restrict__ x, const float* __restrict__ pre_w,
    const float* __restrict__ pre_b, const float* __restrict__ post_w,
    const float* __restrict__ post_b, const float* __restrict__ w_ry,
    const float* __restrict__ w_rz, float* __restrict__ out, int B) {
    // Block-shared weight trig: [0..39] RY (layers; row 0 unused),
    // [40..79] RZ. Index l*10+q within each half.
    __shared__ float2 sh_trig[80];
    {
        int t = threadIdx.x;
        if (t < 80) {
            float ang = (t < 40 ? w_ry[t] : w_rz[t - 40]) * 0.5f;
            float sv, cv;
            __sincosf(ang, &sv, &cv);
            sh_trig[t] = make_float2(cv, sv);
        }
    }
    __syncthreads();

    const int lane = threadIdx.x & 63;
    const int wid = threadIdx.x >> 6;
    const int b = blockIdx.x * 4 + wid;
    if (b >= B) return;

    const int a32 = (lane ^ 32) << 2;

    // Probe permlane*_swap direction (wave-uniform).
    bool cv16 = false, cv32 = false;
#ifdef HAVE_PL16
    {
        auto r = __builtin_amdgcn_permlane16_swap(lane, lane, false, false);
        cv16 = ((int)r[0] == (lane & ~16));
    }
#endif
#ifdef HAVE_PL32
    {
        auto r = __builtin_amdgcn_permlane32_swap(lane, lane, false, false);
        cv32 = ((int)r[0] == (lane & ~32));
    }
#endif

    const int h0 = lane ^ ((lane & 1) ? 32 : 0);
    const int cA = g_of(h0) << 2;
    const int cB = g_of(h0 ^ 32) << 2;

    // ---- q_in[b, i] = x[b] . pre_w[i] + pre_b[i]  (float4 loads) ----
    float th[10];
#pragma unroll
    for (int i = 0; i < 10; ++i) th[i] = 0.f;
    const float4* xb4 = reinterpret_cast<const float4*>(x + (size_t)b * 512);
    const float4* pw4 = reinterpret_cast<const float4*>(pre_w);
#pragma unroll
    for (int k = 0; k < 2; ++k) {
        const int idx = lane + 64 * k;
        const float4 xv = xb4[idx];
#pragma unroll
        for (int i = 0; i < 10; ++i) {
            const float4 wv = pw4[i * 128 + idx];
            th[i] = fmaf(xv.x, wv.x, th[i]);
            th[i] = fmaf(xv.y, wv.y, th[i]);
            th[i] = fmaf(xv.z, wv.z, th[i]);
            th[i] = fmaf(xv.w, wv.w, th[i]);
        }
    }
#pragma unroll
    for (int i = 0; i < 10; ++i) th[i] = wave_sum(th[i], a32) + pre_b[i];

    // ================= layer 0 folded into the initial state ==============
    // Initial RY(th_q) and layer-0 RY(w_ry[0,q]) act on the same qubit with
    // only other-qubit gates between -> compose additively. The pre-CNOT
    // layer-0 state is then a product state; apply the layer-0 RZ phases
    // per-qubit and build the complex product state directly.
    float f0r[10], f0i[10], f1r[10], f1i[10];
#pragma unroll
    for (int q = 0; q < 10; ++q) {
        float hh = 0.5f * (th[q] + w_ry[q]);  // w_ry row 0 (raw angle)
        float sh_, ch_;
        __sincosf(hh, &sh_, &ch_);
        float2 z = sh_trig[40 + q];           // (cos, sin) of w_rz[0,q]/2
        f0r[q] = ch_ * z.x;  f0i[q] = -ch_ * z.y;   // e^{-i z}
        f1r[q] = sh_ * z.x;  f1i[q] =  sh_ * z.y;   // e^{+i z}
    }
    float Lr, Li;
    {
        int bq = (lane >> 5) & 1;
        Lr = bq ? f1r[0] : f0r[0];
        Li = bq ? f1i[0] : f0i[0];
#pragma unroll
        for (int q = 1; q < 6; ++q) {
            int bb = (lane >> (5 - q)) & 1;
            float br = bb ? f1r[q] : f0r[q];
            float bi = bb ? f1i[q] : f0i[q];
            float nr = Lr * br - Li * bi;
            float ni = Lr * bi + Li * br;
            Lr = nr; Li = ni;
        }
    }
    float t67r[4], t67i[4], t89r[4], t89i[4];
#pragma unroll
    for (int j = 0; j < 4; ++j) {
        float ar = (j >> 1) ? f1r[6] : f0r[6];  // qubit6 <-> reg bit 3
        float ai = (j >> 1) ? f1i[6] : f0i[6];
        float br = (j & 1) ? f1r[7] : f0r[7];   // qubit7 <-> reg bit 2
        float bi = (j & 1) ? f1i[7] : f0i[7];
        float pr = ar * br - ai * bi;
        float pi = ar * bi + ai * br;
        t67r[j] = pr * Lr - pi * Li;            // lane factor folded in
        t67i[j] = pr * Li + pi * Lr;
        float cr_ = (j >> 1) ? f1r[8] : f0r[8]; // qubit8 <-> reg bit 1
        float ci_ = (j >> 1) ? f1i[8] : f0i[8];
        float dr = (j & 1) ? f1r[9] : f0r[9];   // qubit9 <-> reg bit 0
        float di = (j & 1) ? f1i[9] : f0i[9];
        t89r[j] = cr_ * dr - ci_ * di;
        t89i[j] = cr_ * di + ci_ * dr;
    }
    float re[16], im[16];
#pragma unroll
    for (int r = 0; r < 16; ++r) {
        const int j = r >> 2, k = r & 3;
        re[r] = t67r[j] * t89r[k] - t67i[j] * t89i[k];
        im[r] = t67r[j] * t89i[k] + t67i[j] * t89r[k];
    }
    cnot_ring(re, im, cA, cB, lane);

    // ================= layers 1..3 (complex), fully unrolled ==============
#pragma unroll
    for (int l = 1; l < 4; ++l) {
        float yc[10], ys[10], zc[10], zs[10];
#pragma unroll
        for (int q = 0; q < 10; ++q) {
            float2 v = sh_trig[l * 10 + q];
            yc[q] = v.x; ys[q] = v.y;
            float2 w = sh_trig[40 + l * 10 + q];
            zc[q] = w.x; zs[q] = w.y;
        }
        apply_ry<9>(re, im, yc[0], ys[0], lane, a32, cv16, cv32);
        apply_ry<8>(re, im, yc[1], ys[1], lane, a32, cv16, cv32);
        apply_ry<7>(re, im, yc[2], ys[2], lane, a32, cv16, cv32);
        apply_ry<6>(re, im, yc[3], ys[3], lane, a32, cv16, cv32);
        apply_ry<5>(re, im, yc[4], ys[4], lane, a32, cv16, cv32);
        apply_ry<4>(re, im, yc[5], ys[5], lane, a32, cv16, cv32);
        apply_ry<3>(re, im, yc[6], ys[6], lane, a32, cv16, cv32);
        apply_ry<2>(re, im, yc[7], ys[7], lane, a32, cv16, cv32);
        apply_ry<1>(re, im, yc[8], ys[8], lane, a32, cv16, cv32);
        apply_ry<0>(re, im, yc[9], ys[9], lane, a32, cv16, cv32);

        float p67r[4], p67i[4], p89r[4], p89i[4];
        build_rz_tables(zc, zs, lane, p67r, p67i, p89r, p89i);
#pragma unroll
        for (int r = 0; r < 16; ++r) {
            const int j = r >> 2, k = r & 3;
            float t_r = re[r] * p67r[j] - im[r] * p67i[j];
            float t_i = re[r] * p67i[j] + im[r] * p67r[j];
            re[r] = t_r * p89r[k] - t_i * p89i[k];
            im[r] = t_r * p89i[k] + t_i * p89r[k];
        }
        cnot_ring(re, im, cA, cB, lane);
    }

    // ---- out[b] = sum_s |psi_s|^2 * C(s) + post_b ----
    float laneC = 0.f;
#pragma unroll
    for (int j = 0; j < 6; ++j) {
        int bit = (lane >> (5 - j)) & 1;
        laneC += post_w[j] * (1.f - 2.f * (float)bit);
    }
    const float w6 = post_w[6], w7 = post_w[7], w8 = post_w[8], w9 = post_w[9];
    float base67[4], m89[4];
#pragma unroll
    for (int j = 0; j < 4; ++j) {
        base67[j] = laneC + ((j >> 1) ? -w6 : w6) + ((j & 1) ? -w7 : w7);
        m89[j] = ((j >> 1) ? -w8 : w8) + ((j & 1) ? -w9 : w9);
    }
    float acc = 0.f;
#pragma unroll
    for (int r = 0; r < 16; ++r) {
        float p = fmaf(re[r], re[r], im[r] * im[r]);
        acc = fmaf(p, base67[r >> 2] + m89[r & 3], acc);
    }
    acc = wave_sum(acc, a32);
    if (lane == 0) out[b] = acc + post_b[0];
}

extern "C" void kernel_launch(void* const* d_in, const int* in_sizes, int n_in,
                              void* d_out, int out_size, void* d_ws, size_t ws_size,
                              hipStream_t stream) {
    const float* x      = (const float*)d_in[0];
    const float* pre_w  = (const float*)d_in[1];
    const float* pre_b  = (const float*)d_in[2];
    const float* post_w = (const float*)d_in[3];
    const float* post_b = (const float*)d_in[4];
    const float* w_ry   = (const float*)d_in[5];
    const float* w_rz   = (const float*)d_in[6];
    float* out = (float*)d_out;
    (void)d_ws; (void)ws_size;

    const int B = in_sizes[0] / 512;  // 4096

    dqc_main_kernel<<<(B + 3) / 4, 256, 0, stream>>>(x, pre_w, pre_b, post_w,
                                                     post_b, w_ry, w_rz, out, B);
}